// Round 1
// baseline (212.127 us; speedup 1.0000x reference)
//
#include <hip/hip_runtime.h>
#include <hip/hip_bf16.h>

#define N_NODES  50000
#define NODE_DIM 256
#define HIDDEN   512
#define N_EDGES  500000
#define M_PAD    50048   // 391 * 128
#define NCAT     1024    // 2 * HIDDEN
#define KDIM     256

typedef __attribute__((ext_vector_type(8))) unsigned short ushort8;
typedef __attribute__((ext_vector_type(4))) unsigned short ushort4v;
typedef __attribute__((ext_vector_type(8))) __bf16 bf16x8;
typedef __attribute__((ext_vector_type(4))) float f32x4;

__device__ __forceinline__ unsigned short f2bf(float f) {
  unsigned int u = __builtin_bit_cast(unsigned int, f);
  u += 0x7fffu + ((u >> 16) & 1u);   // round-to-nearest-even
  return (unsigned short)(u >> 16);
}
__device__ __forceinline__ float bf2f(unsigned short s) {
  return __builtin_bit_cast(float, ((unsigned int)s) << 16);
}

__device__ __forceinline__ void gload16(const void* g, void* l) {
  __builtin_amdgcn_global_load_lds(
      (__attribute__((address_space(1))) void*)(g),
      (__attribute__((address_space(3))) void*)(l),
      16, 0, 0);
}

// ---------------- convert x (f32 -> bf16), zero the M padding rows ----------
__global__ void convert_x_kernel(const float* __restrict__ x, unsigned short* __restrict__ xb) {
  const int total4 = M_PAD * NODE_DIM / 4;
  const int valid4 = N_NODES * NODE_DIM / 4;
  for (int i = blockIdx.x * blockDim.x + threadIdx.x; i < total4; i += gridDim.x * blockDim.x) {
    ushort4v o;
    if (i < valid4) {
      float4 v = ((const float4*)x)[i];
      o[0] = f2bf(v.x); o[1] = f2bf(v.y); o[2] = f2bf(v.z); o[3] = f2bf(v.w);
    } else {
      o[0] = 0; o[1] = 0; o[2] = 0; o[3] = 0;
    }
    ((ushort4v*)xb)[i] = o;
  }
}

// ---- build Wcat^T bf16 [NCAT][KDIM]: Wt[n][k] = W1[(n<512 ? k : 256+k)][n&511]
__global__ void convert_w_kernel(const float* __restrict__ W1, unsigned short* __restrict__ wt) {
  int i = blockIdx.x * blockDim.x + threadIdx.x;
  if (i >= NCAT * KDIM) return;
  int n = i / KDIM;
  int k = i - n * KDIM;
  int srow = (n >= HIDDEN) ? (NODE_DIM + k) : k;
  int scol = n & (HIDDEN - 1);
  wt[i] = f2bf(W1[srow * HIDDEN + scol]);
}

// ---------------- GEMM: C[M_PAD, NCAT] = Xb[M_PAD, 256] @ Wcat, bf16 out ----
// m97-style: 128x128 tile, 4 waves (2x2), BK=32, global_load_lds width 16.
__global__ __launch_bounds__(256, 2) void gemm_kernel(
    const unsigned short* __restrict__ Xb,   // [M_PAD][KDIM]
    const unsigned short* __restrict__ Wt,   // [NCAT][KDIM]  (B^T layout)
    unsigned short* __restrict__ Cb) {       // [M_PAD][NCAT]
  __shared__ unsigned short As[128 * 32];
  __shared__ unsigned short Bs[128 * 32];
  const int t = threadIdx.x;
  const int w = t >> 6;
  const int lane = t & 63;
  const int bid = blockIdx.x;
  const int tileM = bid >> 3;   // NCAT/128 = 8 column tiles
  const int tileN = bid & 7;
  const int wm = w >> 1, wn = w & 1;

  f32x4 acc[4][4] = {};

  const int rowA0 = tileM * 128;
  const int rowB0 = tileN * 128;
  const int rstage = t >> 2;         // 0..63
  const int cstage = (t & 3) * 8;    // k element offset of this thread's 16B

  for (int kk = 0; kk < KDIM; kk += 32) {
#pragma unroll
    for (int i = 0; i < 2; ++i) {
      const unsigned short* srcA = Xb + (size_t)(rowA0 + i * 64 + rstage) * KDIM + kk + cstage;
      gload16(srcA, (char*)As + i * 4096 + w * 1024);
      const unsigned short* srcB = Wt + (size_t)(rowB0 + i * 64 + rstage) * KDIM + kk + cstage;
      gload16(srcB, (char*)Bs + i * 4096 + w * 1024);
    }
    __syncthreads();

    bf16x8 a[4], b[4];
#pragma unroll
    for (int fm = 0; fm < 4; ++fm)
      a[fm] = *(const bf16x8*)&As[(wm * 64 + fm * 16 + (lane & 15)) * 32 + (lane >> 4) * 8];
#pragma unroll
    for (int fn = 0; fn < 4; ++fn)
      b[fn] = *(const bf16x8*)&Bs[(wn * 64 + fn * 16 + (lane & 15)) * 32 + (lane >> 4) * 8];
#pragma unroll
    for (int fm = 0; fm < 4; ++fm)
#pragma unroll
      for (int fn = 0; fn < 4; ++fn)
        acc[fm][fn] = __builtin_amdgcn_mfma_f32_16x16x32_bf16(a[fm], b[fn], acc[fm][fn], 0, 0, 0);
    __syncthreads();
  }

  const int row0 = tileM * 128 + wm * 64;
  const int col0 = tileN * 128 + wn * 64;
#pragma unroll
  for (int fm = 0; fm < 4; ++fm)
#pragma unroll
    for (int fn = 0; fn < 4; ++fn)
#pragma unroll
      for (int r = 0; r < 4; ++r) {
        int row = row0 + fm * 16 + (lane >> 4) * 4 + r;
        int col = col0 + fn * 16 + (lane & 15);
        Cb[(size_t)row * NCAT + col] = f2bf(acc[fm][fn][r]);
      }
}

// ---------------- edge pass: out[e] = relu(A[row]+B[col]+b1) . W2 + b2 ------
// one wave per edge; lane l owns elements l*8 .. l*8+7
__global__ __launch_bounds__(256) void edge_kernel(
    const unsigned short* __restrict__ Cb,   // [M_PAD][NCAT]; [:,0:512]=A, [:,512:1024]=B
    const int* __restrict__ ei,              // [2][N_EDGES] int32
    const float* __restrict__ b1,            // [512]
    const float* __restrict__ W2,            // [512]
    const float* __restrict__ b2,            // [1]
    float* __restrict__ out) {               // [N_EDGES]
  const int lane = threadIdx.x & 63;
  const int wid = blockIdx.x * 4 + (threadIdx.x >> 6);
  const int nw = gridDim.x * 4;
  const int base = lane * 8;

  float b1r[8], w2r[8];
  {
    float4 v0 = *(const float4*)&b1[base];
    float4 v1 = *(const float4*)&b1[base + 4];
    b1r[0] = v0.x; b1r[1] = v0.y; b1r[2] = v0.z; b1r[3] = v0.w;
    b1r[4] = v1.x; b1r[5] = v1.y; b1r[6] = v1.z; b1r[7] = v1.w;
    float4 u0 = *(const float4*)&W2[base];
    float4 u1 = *(const float4*)&W2[base + 4];
    w2r[0] = u0.x; w2r[1] = u0.y; w2r[2] = u0.z; w2r[3] = u0.w;
    w2r[4] = u1.x; w2r[5] = u1.y; w2r[6] = u1.z; w2r[7] = u1.w;
  }
  const float bias2 = b2[0];

  for (int e = wid; e < N_EDGES; e += nw) {
    const int r = ei[e];
    const int c = ei[N_EDGES + e];
    ushort8 av = *(const ushort8*)(Cb + (size_t)r * NCAT + base);
    ushort8 bv = *(const ushort8*)(Cb + (size_t)c * NCAT + HIDDEN + base);
    float acc = 0.f;
#pragma unroll
    for (int j = 0; j < 8; ++j) {
      float h = bf2f(av[j]) + bf2f(bv[j]) + b1r[j];
      h = fmaxf(h, 0.f);
      acc = fmaf(h, w2r[j], acc);
    }
#pragma unroll
    for (int off = 32; off; off >>= 1)
      acc += __shfl_xor(acc, off, 64);
    if (lane == 0) out[e] = acc + bias2;
  }
}

extern "C" void kernel_launch(void* const* d_in, const int* in_sizes, int n_in,
                              void* d_out, int out_size, void* d_ws, size_t ws_size,
                              hipStream_t stream) {
  const float* x  = (const float*)d_in[0];
  const int*   ei = (const int*)d_in[1];
  const float* W1 = (const float*)d_in[2];
  const float* b1 = (const float*)d_in[3];
  const float* W2 = (const float*)d_in[4];
  const float* b2 = (const float*)d_in[5];
  float* out = (float*)d_out;

  char* ws = (char*)d_ws;
  const size_t xb_bytes = (size_t)M_PAD * KDIM * 2;      // 25,624,576
  const size_t wt_bytes = (size_t)NCAT * KDIM * 2;       //    524,288
  unsigned short* xb = (unsigned short*)ws;
  unsigned short* wt = (unsigned short*)(ws + xb_bytes);
  unsigned short* cb = (unsigned short*)(ws + xb_bytes + wt_bytes);  // 102,498,304

  hipLaunchKernelGGL(convert_x_kernel, dim3(2048), dim3(256), 0, stream, x, xb);
  hipLaunchKernelGGL(convert_w_kernel, dim3((NCAT * KDIM + 255) / 256), dim3(256), 0, stream, W1, wt);
  hipLaunchKernelGGL(gemm_kernel, dim3((M_PAD / 128) * (NCAT / 128)), dim3(256), 0, stream, xb, wt, cb);
  hipLaunchKernelGGL(edge_kernel, dim3(2048), dim3(256), 0, stream, cb, ei, b1, W2, b2, out);
}